// Round 1
// baseline (1063.193 us; speedup 1.0000x reference)
//
#include <hip/hip_runtime.h>
#include <cstddef>
#include <cstdint>

constexpr int NN = 50000;          // nodes
constexpr int NE = 800000;         // edges (no self loops)
constexpr int ET = NE + NN;        // edges + self loops
constexpr int NB = 50;             // graphs

__device__ __forceinline__ float eluf(float x) { return x > 0.f ? x : expm1f(x); }

// ---------------- kernel: edge encoder MLP + sum(ew) ----------------
__global__ void edge_mlp_kernel(const float* __restrict__ ea,
                                const float* __restrict__ w1, const float* __restrict__ b1,
                                const float* __restrict__ w2, const float* __restrict__ b2,
                                float* __restrict__ ew, float* __restrict__ ew_sum) {
    __shared__ float sw1[320];
    __shared__ float sb1[64];
    __shared__ float sw2[64];
    int t = threadIdx.x;
    for (int i = t; i < 320; i += 256) sw1[i] = w1[i];
    if (t < 64) { sb1[t] = b1[t]; sw2[t] = w2[t]; }
    __syncthreads();
    int e = blockIdx.x * 256 + t;
    float val = 0.f;
    if (e < NE) {
        float a0 = ea[e*5+0], a1 = ea[e*5+1], a2 = ea[e*5+2], a3 = ea[e*5+3], a4 = ea[e*5+4];
        float acc = b2[0];
        #pragma unroll 8
        for (int j = 0; j < 64; ++j) {
            float hj = sb1[j] + a0*sw1[j] + a1*sw1[64+j] + a2*sw1[128+j] + a3*sw1[192+j] + a4*sw1[256+j];
            acc += fmaxf(hj, 0.f) * sw2[j];
        }
        val = 1.f / (1.f + expf(-acc));
        ew[e] = val;
    }
    __shared__ float red[256];
    red[t] = val;
    __syncthreads();
    for (int off = 128; off > 0; off >>= 1) {
        if (t < off) red[t] += red[t + off];
        __syncthreads();
    }
    if (t == 0) atomicAdd(ew_sum, red[0]);
}

// ---------------- kernel: fill self-loop ew with mean; compute ce[l][h] ----------------
__global__ void prep_kernel(const float* __restrict__ We, const float* __restrict__ att_e,
                            const float* __restrict__ ew_sum, float* __restrict__ ew,
                            float* __restrict__ ce) {
    int i = blockIdx.x * 256 + threadIdx.x;
    float mean = ew_sum[0] * (1.f / (float)NE);
    if (i < NN) ew[NE + i] = mean;
    if (i < 12) {
        int l = i >> 2, h = i & 3;
        float s = 0.f;
        for (int c = 0; c < 64; ++c)
            s += We[l*256 + h*64 + c] * att_e[l*256 + h*64 + c];
        ce[i] = s;
    }
}

// ---------------- CSR build ----------------
__global__ void hist_kernel(const int* __restrict__ ei_dst, int* __restrict__ deg) {
    int e = blockIdx.x * 256 + threadIdx.x;
    if (e >= ET) return;
    int d = (e < NE) ? ei_dst[e] : (e - NE);
    atomicAdd(&deg[d], 1);
}

__global__ void scan_kernel(const int* __restrict__ deg, int* __restrict__ row_ptr) {
    __shared__ int sdata[1024];
    int t = threadIdx.x;
    int carry = 0;
    if (t == 0) row_ptr[0] = 0;
    for (int base = 0; base < NN; base += 1024) {
        int i = base + t;
        int v = (i < NN) ? deg[i] : 0;
        sdata[t] = v;
        __syncthreads();
        for (int off = 1; off < 1024; off <<= 1) {
            int tv = (t >= off) ? sdata[t - off] : 0;
            __syncthreads();
            sdata[t] += tv;
            __syncthreads();
        }
        if (i < NN) row_ptr[i + 1] = carry + sdata[t];
        carry += sdata[1023];
        __syncthreads();
    }
}

__global__ void scatter_kernel(const int* __restrict__ ei_dst, const int* __restrict__ row_ptr,
                               int* __restrict__ fill, int* __restrict__ csr) {
    int e = blockIdx.x * 256 + threadIdx.x;
    if (e >= ET) return;
    int d = (e < NE) ? ei_dst[e] : (e - NE);
    int pos = atomicAdd(&fill[d], 1);
    csr[row_ptr[d] + pos] = e;
}

// ---------------- kernel: h = xin @ W, fused alpha_src/alpha_dst ----------------
// 8 nodes per 256-thread block; wave w holds head w's 64 channels.
template <int FIN>
__global__ void node_transform(const float* __restrict__ xin, const float* __restrict__ W,
                               const float* __restrict__ a_s, const float* __restrict__ a_d,
                               float* __restrict__ h, float* __restrict__ asrc,
                               float* __restrict__ adst) {
    const int t = threadIdx.x;
    const int n0 = blockIdx.x * 8;
    __shared__ float xr[8 * FIN];
    for (int i = t; i < 8 * FIN; i += 256) {
        int node = n0 + i / FIN;
        xr[i] = (node < NN) ? xin[(size_t)node * FIN + (i % FIN)] : 0.f;
    }
    __syncthreads();
    float acc[8];
    #pragma unroll
    for (int i = 0; i < 8; ++i) acc[i] = 0.f;
    for (int k = 0; k < FIN; ++k) {
        float wv = W[k * 256 + t];
        #pragma unroll
        for (int i = 0; i < 8; ++i) acc[i] += xr[i * FIN + k] * wv;
    }
    float as_t = a_s[t], ad_t = a_d[t];
    int lane = t & 63, head = t >> 6;
    for (int i = 0; i < 8; ++i) {
        int node = n0 + i;
        if (node >= NN) break;
        h[(size_t)node * 256 + t] = acc[i];
        float vs = acc[i] * as_t, vd = acc[i] * ad_t;
        #pragma unroll
        for (int mask = 1; mask <= 32; mask <<= 1) {
            vs += __shfl_xor(vs, mask);
            vd += __shfl_xor(vd, mask);
        }
        if (lane == 0) {
            asrc[node * 4 + head] = vs;
            adst[node * 4 + head] = vd;
        }
    }
}

// ---------------- kernel: per-dst-node segment softmax + aggregation ----------------
// One wave (64 lanes) per destination node. 4 waves / 256-thread block.
__global__ void gat_aggregate(const float* __restrict__ h, const float* __restrict__ asrc,
                              const float* __restrict__ adst, const float* __restrict__ ew,
                              const float* __restrict__ ce_l, const float* __restrict__ bias_l,
                              const int* __restrict__ ei_src, const int* __restrict__ row_ptr,
                              const int* __restrict__ csr, float* __restrict__ xi,
                              int residual) {
    int widx = (blockIdx.x * 256 + threadIdx.x) >> 6;   // node
    if (widx >= NN) return;
    int lane = threadIdx.x & 63;
    int start = row_ptr[widx], end = row_ptr[widx + 1];

    // ---- pass 1: per-head max of leaky_relu(alpha) ----
    int h1 = lane & 3;          // head for pass 1
    int j = lane >> 2;          // edge slot 0..15
    float adst1 = adst[widx * 4 + h1];
    float ce1 = ce_l[h1];
    float m = -1e30f;
    for (int b0 = start; b0 < end; b0 += 16) {
        int ei = b0 + j;
        if (ei < end) {
            int eid = csr[ei];
            int s = (eid < NE) ? ei_src[eid] : (eid - NE);
            float al = asrc[s * 4 + h1] + adst1 + ew[eid] * ce1;
            al = al > 0.f ? al : 0.2f * al;
            m = fmaxf(m, al);
        }
    }
    #pragma unroll
    for (int mask = 4; mask <= 32; mask <<= 1) m = fmaxf(m, __shfl_xor(m, mask));
    int head2 = lane >> 4;      // head for pass 2 (channel layout)
    float mh = __shfl(m, head2);  // lane h (h<4) holds max for head h

    // ---- pass 2: p = exp(al-m); accumulate sum(p) and sum(p * h[src]) ----
    float adst2 = adst[widx * 4 + head2];
    float ce2 = ce_l[head2];
    float psum = 0.f;
    float ax = 0.f, ay = 0.f, az = 0.f, aw = 0.f;
    for (int ei = start; ei < end; ++ei) {
        int eid = csr[ei];
        int s = (eid < NE) ? ei_src[eid] : (eid - NE);
        float al = asrc[s * 4 + head2] + adst2 + ew[eid] * ce2;
        al = al > 0.f ? al : 0.2f * al;
        float p = expf(al - mh);
        psum += p;
        const float4 f = *(const float4*)(h + (size_t)s * 256 + lane * 4);
        ax += p * f.x; ay += p * f.y; az += p * f.z; aw += p * f.w;
    }
    float inv = 1.f / (psum + 1e-16f);
    ax *= inv; ay *= inv; az *= inv; aw *= inv;

    // ---- head mean: lanes {c,c+16,c+32,c+48} hold the 4 heads of channel group c ----
    #pragma unroll
    for (int mask = 16; mask <= 32; mask <<= 1) {
        ax += __shfl_xor(ax, mask);
        ay += __shfl_xor(ay, mask);
        az += __shfl_xor(az, mask);
        aw += __shfl_xor(aw, mask);
    }
    if (lane < 16) {
        int c0 = lane * 4;
        float4 v;
        v.x = 0.25f * ax + bias_l[c0 + 0];
        v.y = 0.25f * ay + bias_l[c0 + 1];
        v.z = 0.25f * az + bias_l[c0 + 2];
        v.w = 0.25f * aw + bias_l[c0 + 3];
        float* xo = xi + (size_t)widx * 64 + c0;
        if (residual) {
            const float4 p = *(const float4*)xo;
            v.x += p.x; v.y += p.y; v.z += p.z; v.w += p.w;
        }
        v.x = eluf(v.x); v.y = eluf(v.y); v.z = eluf(v.z); v.w = eluf(v.w);
        *(float4*)xo = v;
    }
}

// ---------------- kernel: LN + 2-layer MLP on the 50 target nodes ----------------
__global__ void readout_kernel(const float* __restrict__ xi, const int* __restrict__ batch,
                               const float* __restrict__ ln_g, const float* __restrict__ ln_b,
                               const float* __restrict__ l1w, const float* __restrict__ l1b,
                               const float* __restrict__ l2w, const float* __restrict__ l2b,
                               float* __restrict__ out) {
    int b = blockIdx.x;
    int t = threadIdx.x;   // 64 threads, one wave
    __shared__ int tg_s;
    if (t == 0) {
        int lo = 0, hi = NN;   // searchsorted left: first idx with batch[idx] >= b
        while (lo < hi) {
            int mid = (lo + hi) >> 1;
            if (batch[mid] < b) lo = mid + 1; else hi = mid;
        }
        tg_s = lo;
    }
    __syncthreads();
    int tg = tg_s;
    float x = xi[(size_t)tg * 64 + t];
    float s = x;
    #pragma unroll
    for (int mask = 1; mask <= 32; mask <<= 1) s += __shfl_xor(s, mask);
    float mu = s * (1.f / 64.f);
    float d = x - mu;
    float v = d * d;
    #pragma unroll
    for (int mask = 1; mask <= 32; mask <<= 1) v += __shfl_xor(v, mask);
    float var = v * (1.f / 64.f);
    float xn = d * rsqrtf(var + 1e-5f) * ln_g[t] + ln_b[t];
    __shared__ float sx[64];
    sx[t] = xn;
    __syncthreads();
    float acc = l1b[t];
    for (int k = 0; k < 64; ++k) acc += sx[k] * l1w[k * 64 + t];
    acc = eluf(acc);
    __shared__ float st[64];
    st[t] = acc;
    __syncthreads();
    if (t < 3) {
        float o = l2b[t];
        for (int k = 0; k < 64; ++k) o += st[k] * l2w[k * 3 + t];
        out[b * 3 + t] = o;
    }
}

extern "C" void kernel_launch(void* const* d_in, const int* in_sizes, int n_in,
                              void* d_out, int out_size, void* d_ws, size_t ws_size,
                              hipStream_t stream) {
    const float* x        = (const float*)d_in[0];
    const int*   ei       = (const int*)d_in[1];     // (2,E): [0..E)=src, [E..2E)=dst
    const float* ea       = (const float*)d_in[2];
    const int*   batch    = (const int*)d_in[3];
    const float* ee_w1    = (const float*)d_in[4];
    const float* ee_b1    = (const float*)d_in[5];
    const float* ee_w2    = (const float*)d_in[6];
    const float* ee_b2    = (const float*)d_in[7];
    const float* W1       = (const float*)d_in[8];
    const float* Ws       = (const float*)d_in[9];
    const float* att_src  = (const float*)d_in[10];
    const float* att_dst  = (const float*)d_in[11];
    const float* We       = (const float*)d_in[12];
    const float* att_e    = (const float*)d_in[13];
    const float* bias     = (const float*)d_in[14];
    const float* ln_g     = (const float*)d_in[15];
    const float* ln_b     = (const float*)d_in[16];
    const float* lin1_w   = (const float*)d_in[17];
    const float* lin1_b   = (const float*)d_in[18];
    const float* lin2_w   = (const float*)d_in[19];
    const float* lin2_b   = (const float*)d_in[20];
    float* out = (float*)d_out;

    // ---- workspace carve-up (256B aligned) ----
    char* ws = (char*)d_ws;
    size_t off = 0;
    auto alloc = [&](size_t bytes) -> char* {
        char* p = ws + off;
        off += (bytes + 255) & ~(size_t)255;
        return p;
    };
    float* ew      = (float*)alloc((size_t)ET * 4);
    float* ew_sum  = (float*)alloc(4);
    float* ce      = (float*)alloc(12 * 4);
    float* hbuf    = (float*)alloc((size_t)NN * 256 * 4);
    float* asrc    = (float*)alloc((size_t)NN * 4 * 4);
    float* adst    = (float*)alloc((size_t)NN * 4 * 4);
    float* xi      = (float*)alloc((size_t)NN * 64 * 4);
    int*   deg     = (int*)alloc((size_t)NN * 4);       // reused as fill
    int*   row_ptr = (int*)alloc((size_t)(NN + 1) * 4);
    int*   csr     = (int*)alloc((size_t)ET * 4);
    (void)ws_size; (void)n_in; (void)in_sizes; (void)out_size;

    const int* ei_src = ei;
    const int* ei_dst = ei + NE;

    // 1. edge encoder
    hipMemsetAsync(ew_sum, 0, 4, stream);
    edge_mlp_kernel<<<(NE + 255) / 256, 256, 0, stream>>>(ea, ee_w1, ee_b1, ee_w2, ee_b2, ew, ew_sum);
    prep_kernel<<<(NN + 255) / 256, 256, 0, stream>>>(We, att_e, ew_sum, ew, ce);

    // 2. CSR by dst
    hipMemsetAsync(deg, 0, (size_t)NN * 4, stream);
    hist_kernel<<<(ET + 255) / 256, 256, 0, stream>>>(ei_dst, deg);
    scan_kernel<<<1, 1024, 0, stream>>>(deg, row_ptr);
    hipMemsetAsync(deg, 0, (size_t)NN * 4, stream);
    scatter_kernel<<<(ET + 255) / 256, 256, 0, stream>>>(ei_dst, row_ptr, deg, csr);

    // 3. three GAT layers
    const int ntBlocks = (NN + 7) / 8;
    const int agBlocks = (NN + 3) / 4;
    // layer 0
    node_transform<16><<<ntBlocks, 256, 0, stream>>>(x, W1, att_src + 0 * 256, att_dst + 0 * 256,
                                                     hbuf, asrc, adst);
    gat_aggregate<<<agBlocks, 256, 0, stream>>>(hbuf, asrc, adst, ew, ce + 0 * 4, bias + 0 * 64,
                                                ei_src, row_ptr, csr, xi, 0);
    // layers 1..2 (residual)
    for (int l = 0; l < 2; ++l) {
        node_transform<64><<<ntBlocks, 256, 0, stream>>>(xi, Ws + (size_t)l * 64 * 256,
                                                         att_src + (l + 1) * 256,
                                                         att_dst + (l + 1) * 256,
                                                         hbuf, asrc, adst);
        gat_aggregate<<<agBlocks, 256, 0, stream>>>(hbuf, asrc, adst, ew, ce + (l + 1) * 4,
                                                    bias + (l + 1) * 64, ei_src, row_ptr, csr,
                                                    xi, 1);
    }

    // 4. readout
    readout_kernel<<<NB, 64, 0, stream>>>(xi, batch, ln_g, ln_b, lin1_w, lin1_b, lin2_w, lin2_b, out);
}

// Round 2
// 735.898 us; speedup vs baseline: 1.4448x; 1.4448x over previous
//
#include <hip/hip_runtime.h>
#include <cstddef>
#include <cstdint>

constexpr int NN = 50000;          // nodes
constexpr int NE = 800000;         // edges (no self loops)
constexpr int ET = NE + NN;        // edges + self loops
constexpr int NB = 50;             // graphs

__device__ __forceinline__ float eluf(float x) { return x > 0.f ? x : expm1f(x); }

// round-to-nearest-even fp32 -> bf16 (as ushort)
__device__ __forceinline__ unsigned short f2bf(float f) {
    unsigned int u = __float_as_uint(f);
    unsigned int r = (u + 0x7fffu + ((u >> 16) & 1u)) >> 16;
    return (unsigned short)r;
}

// ---------------- kernel: edge encoder MLP + sum(ew) ----------------
__global__ void edge_mlp_kernel(const float* __restrict__ ea,
                                const float* __restrict__ w1, const float* __restrict__ b1,
                                const float* __restrict__ w2, const float* __restrict__ b2,
                                float* __restrict__ ew, float* __restrict__ ew_sum) {
    __shared__ float sw1[320];
    __shared__ float sb1[64];
    __shared__ float sw2[64];
    int t = threadIdx.x;
    for (int i = t; i < 320; i += 256) sw1[i] = w1[i];
    if (t < 64) { sb1[t] = b1[t]; sw2[t] = w2[t]; }
    __syncthreads();
    int e = blockIdx.x * 256 + t;
    float val = 0.f;
    if (e < NE) {
        float a0 = ea[e*5+0], a1 = ea[e*5+1], a2 = ea[e*5+2], a3 = ea[e*5+3], a4 = ea[e*5+4];
        float acc = b2[0];
        #pragma unroll 8
        for (int j = 0; j < 64; ++j) {
            float hj = sb1[j] + a0*sw1[j] + a1*sw1[64+j] + a2*sw1[128+j] + a3*sw1[192+j] + a4*sw1[256+j];
            acc += fmaxf(hj, 0.f) * sw2[j];
        }
        val = 1.f / (1.f + expf(-acc));
        ew[e] = val;
    }
    __shared__ float red[256];
    red[t] = val;
    __syncthreads();
    for (int off = 128; off > 0; off >>= 1) {
        if (t < off) red[t] += red[t + off];
        __syncthreads();
    }
    if (t == 0) atomicAdd(ew_sum, red[0]);
}

// ---------------- kernel: fill self-loop ew with mean; compute ce[l][h] ----------------
__global__ void prep_kernel(const float* __restrict__ We, const float* __restrict__ att_e,
                            const float* __restrict__ ew_sum, float* __restrict__ ew,
                            float* __restrict__ ce) {
    int i = blockIdx.x * 256 + threadIdx.x;
    float mean = ew_sum[0] * (1.f / (float)NE);
    if (i < NN) ew[NE + i] = mean;
    if (i < 12) {
        int l = i >> 2, h = i & 3;
        float s = 0.f;
        for (int c = 0; c < 64; ++c)
            s += We[l*256 + h*64 + c] * att_e[l*256 + h*64 + c];
        ce[i] = s;
    }
}

// ---------------- CSR build ----------------
__global__ void hist_kernel(const int* __restrict__ ei_dst, int* __restrict__ deg) {
    int e = blockIdx.x * 256 + threadIdx.x;
    if (e >= ET) return;
    int d = (e < NE) ? ei_dst[e] : (e - NE);
    atomicAdd(&deg[d], 1);
}

__global__ void scan_kernel(const int* __restrict__ deg, int* __restrict__ row_ptr) {
    __shared__ int sdata[1024];
    int t = threadIdx.x;
    int carry = 0;
    if (t == 0) row_ptr[0] = 0;
    for (int base = 0; base < NN; base += 1024) {
        int i = base + t;
        int v = (i < NN) ? deg[i] : 0;
        sdata[t] = v;
        __syncthreads();
        for (int off = 1; off < 1024; off <<= 1) {
            int tv = (t >= off) ? sdata[t - off] : 0;
            __syncthreads();
            sdata[t] += tv;
            __syncthreads();
        }
        if (i < NN) row_ptr[i + 1] = carry + sdata[t];
        carry += sdata[1023];
        __syncthreads();
    }
}

// write per-slot src / dst / ew so later kernels have no indirection
__global__ void scatter_kernel(const int* __restrict__ ei_src, const int* __restrict__ ei_dst,
                               const int* __restrict__ row_ptr, const float* __restrict__ ew,
                               int* __restrict__ fill, int* __restrict__ csr_src,
                               int* __restrict__ csr_dst, float* __restrict__ csr_ew) {
    int e = blockIdx.x * 256 + threadIdx.x;
    if (e >= ET) return;
    int d = (e < NE) ? ei_dst[e] : (e - NE);
    int s = (e < NE) ? ei_src[e] : (e - NE);
    int pos = atomicAdd(&fill[d], 1);
    int slot = row_ptr[d] + pos;
    csr_src[slot] = s;
    csr_dst[slot] = d;
    csr_ew[slot] = ew[e];
}

// ---------------- kernel: h = xin @ W (bf16 store), fused alpha_src/alpha_dst ----------------
template <int FIN>
__global__ void node_transform(const float* __restrict__ xin, const float* __restrict__ W,
                               const float* __restrict__ a_s, const float* __restrict__ a_d,
                               unsigned short* __restrict__ hb, float* __restrict__ asrc,
                               float* __restrict__ adst) {
    const int t = threadIdx.x;
    const int n0 = blockIdx.x * 8;
    __shared__ float xr[8 * FIN];
    for (int i = t; i < 8 * FIN; i += 256) {
        int node = n0 + i / FIN;
        xr[i] = (node < NN) ? xin[(size_t)node * FIN + (i % FIN)] : 0.f;
    }
    __syncthreads();
    float acc[8];
    #pragma unroll
    for (int i = 0; i < 8; ++i) acc[i] = 0.f;
    for (int k = 0; k < FIN; ++k) {
        float wv = W[k * 256 + t];
        #pragma unroll
        for (int i = 0; i < 8; ++i) acc[i] += xr[i * FIN + k] * wv;
    }
    float as_t = a_s[t], ad_t = a_d[t];
    int lane = t & 63, head = t >> 6;
    for (int i = 0; i < 8; ++i) {
        int node = n0 + i;
        if (node >= NN) break;
        hb[(size_t)node * 256 + t] = f2bf(acc[i]);
        float vs = acc[i] * as_t, vd = acc[i] * ad_t;
        #pragma unroll
        for (int mask = 1; mask <= 32; mask <<= 1) {
            vs += __shfl_xor(vs, mask);
            vd += __shfl_xor(vd, mask);
        }
        if (lane == 0) {
            asrc[node * 4 + head] = vs;
            adst[node * 4 + head] = vd;
        }
    }
}

// ---------------- kernel: per-slot alpha (leaky-relu'd), edge-parallel ----------------
__global__ void alpha_kernel(const float* __restrict__ asrc, const float* __restrict__ adst,
                             const int* __restrict__ csr_src, const int* __restrict__ csr_dst,
                             const float* __restrict__ csr_ew, const float* __restrict__ ce_l,
                             float4* __restrict__ alpha) {
    int ei = blockIdx.x * 256 + threadIdx.x;
    if (ei >= ET) return;
    int s = csr_src[ei];
    int d = csr_dst[ei];
    float w = csr_ew[ei];
    const float4 as4 = *(const float4*)(asrc + s * 4);
    const float4 ad4 = *(const float4*)(adst + d * 4);
    float4 o;
    float v;
    v = as4.x + ad4.x + w * ce_l[0]; o.x = v > 0.f ? v : 0.2f * v;
    v = as4.y + ad4.y + w * ce_l[1]; o.y = v > 0.f ? v : 0.2f * v;
    v = as4.z + ad4.z + w * ce_l[2]; o.z = v > 0.f ? v : 0.2f * v;
    v = as4.w + ad4.w + w * ce_l[3]; o.w = v > 0.f ? v : 0.2f * v;
    alpha[ei] = o;
}

// ---------------- kernel: per-dst-node segment softmax + aggregation ----------------
// One wave (64 lanes) per destination node. 4 waves / 256-thread block.
__global__ void gat_aggregate(const unsigned short* __restrict__ hb,
                              const float* __restrict__ alphaf,
                              const float* __restrict__ bias_l,
                              const int* __restrict__ csr_src, const int* __restrict__ row_ptr,
                              float* __restrict__ xi, int residual) {
    int widx = (blockIdx.x * 256 + threadIdx.x) >> 6;   // node
    if (widx >= NN) return;
    int lane = threadIdx.x & 63;
    int start = row_ptr[widx], end = row_ptr[widx + 1];

    // ---- pass 1: per-head max of alpha (coalesced: 16 slots x 4 heads per iter) ----
    int h1 = lane & 3;
    int j = lane >> 2;
    float m = -1e30f;
    for (int b0 = start; b0 < end; b0 += 16) {
        int ei = b0 + j;
        if (ei < end) m = fmaxf(m, alphaf[ei * 4 + h1]);
    }
    #pragma unroll
    for (int mask = 4; mask <= 32; mask <<= 1) m = fmaxf(m, __shfl_xor(m, mask));
    int head2 = lane >> 4;
    float mh = __shfl(m, head2);  // lane h (h<4) holds max for head h

    // ---- pass 2: p = exp(al-m); accumulate sum(p) and sum(p * h[src]) ----
    float psum = 0.f;
    float ax = 0.f, ay = 0.f, az = 0.f, aw = 0.f;
    int ei = start;
    for (; ei + 1 < end; ei += 2) {
        int s0 = csr_src[ei];
        int s1 = csr_src[ei + 1];
        float a0 = alphaf[ei * 4 + head2];
        float a1 = alphaf[(ei + 1) * 4 + head2];
        const uint2 q0 = *(const uint2*)(hb + (size_t)s0 * 256 + lane * 4);
        const uint2 q1 = *(const uint2*)(hb + (size_t)s1 * 256 + lane * 4);
        float p0 = expf(a0 - mh);
        float p1 = expf(a1 - mh);
        psum += p0 + p1;
        ax += p0 * __uint_as_float(q0.x << 16) + p1 * __uint_as_float(q1.x << 16);
        ay += p0 * __uint_as_float(q0.x & 0xffff0000u) + p1 * __uint_as_float(q1.x & 0xffff0000u);
        az += p0 * __uint_as_float(q0.y << 16) + p1 * __uint_as_float(q1.y << 16);
        aw += p0 * __uint_as_float(q0.y & 0xffff0000u) + p1 * __uint_as_float(q1.y & 0xffff0000u);
    }
    if (ei < end) {
        int s0 = csr_src[ei];
        float a0 = alphaf[ei * 4 + head2];
        const uint2 q0 = *(const uint2*)(hb + (size_t)s0 * 256 + lane * 4);
        float p0 = expf(a0 - mh);
        psum += p0;
        ax += p0 * __uint_as_float(q0.x << 16);
        ay += p0 * __uint_as_float(q0.x & 0xffff0000u);
        az += p0 * __uint_as_float(q0.y << 16);
        aw += p0 * __uint_as_float(q0.y & 0xffff0000u);
    }
    float inv = 1.f / (psum + 1e-16f);
    ax *= inv; ay *= inv; az *= inv; aw *= inv;

    // ---- head mean: lanes {c,c+16,c+32,c+48} hold the 4 heads of channel group c ----
    #pragma unroll
    for (int mask = 16; mask <= 32; mask <<= 1) {
        ax += __shfl_xor(ax, mask);
        ay += __shfl_xor(ay, mask);
        az += __shfl_xor(az, mask);
        aw += __shfl_xor(aw, mask);
    }
    if (lane < 16) {
        int c0 = lane * 4;
        float4 v;
        v.x = 0.25f * ax + bias_l[c0 + 0];
        v.y = 0.25f * ay + bias_l[c0 + 1];
        v.z = 0.25f * az + bias_l[c0 + 2];
        v.w = 0.25f * aw + bias_l[c0 + 3];
        float* xo = xi + (size_t)widx * 64 + c0;
        if (residual) {
            const float4 p = *(const float4*)xo;
            v.x += p.x; v.y += p.y; v.z += p.z; v.w += p.w;
        }
        v.x = eluf(v.x); v.y = eluf(v.y); v.z = eluf(v.z); v.w = eluf(v.w);
        *(float4*)xo = v;
    }
}

// ---------------- kernel: LN + 2-layer MLP on the 50 target nodes ----------------
__global__ void readout_kernel(const float* __restrict__ xi, const int* __restrict__ batch,
                               const float* __restrict__ ln_g, const float* __restrict__ ln_b,
                               const float* __restrict__ l1w, const float* __restrict__ l1b,
                               const float* __restrict__ l2w, const float* __restrict__ l2b,
                               float* __restrict__ out) {
    int b = blockIdx.x;
    int t = threadIdx.x;   // 64 threads, one wave
    __shared__ int tg_s;
    if (t == 0) {
        int lo = 0, hi = NN;
        while (lo < hi) {
            int mid = (lo + hi) >> 1;
            if (batch[mid] < b) lo = mid + 1; else hi = mid;
        }
        tg_s = lo;
    }
    __syncthreads();
    int tg = tg_s;
    float x = xi[(size_t)tg * 64 + t];
    float s = x;
    #pragma unroll
    for (int mask = 1; mask <= 32; mask <<= 1) s += __shfl_xor(s, mask);
    float mu = s * (1.f / 64.f);
    float d = x - mu;
    float v = d * d;
    #pragma unroll
    for (int mask = 1; mask <= 32; mask <<= 1) v += __shfl_xor(v, mask);
    float var = v * (1.f / 64.f);
    float xn = d * rsqrtf(var + 1e-5f) * ln_g[t] + ln_b[t];
    __shared__ float sx[64];
    sx[t] = xn;
    __syncthreads();
    float acc = l1b[t];
    for (int k = 0; k < 64; ++k) acc += sx[k] * l1w[k * 64 + t];
    acc = eluf(acc);
    __shared__ float st[64];
    st[t] = acc;
    __syncthreads();
    if (t < 3) {
        float o = l2b[t];
        for (int k = 0; k < 64; ++k) o += st[k] * l2w[k * 3 + t];
        out[b * 3 + t] = o;
    }
}

extern "C" void kernel_launch(void* const* d_in, const int* in_sizes, int n_in,
                              void* d_out, int out_size, void* d_ws, size_t ws_size,
                              hipStream_t stream) {
    const float* x        = (const float*)d_in[0];
    const int*   ei       = (const int*)d_in[1];
    const float* ea       = (const float*)d_in[2];
    const int*   batch    = (const int*)d_in[3];
    const float* ee_w1    = (const float*)d_in[4];
    const float* ee_b1    = (const float*)d_in[5];
    const float* ee_w2    = (const float*)d_in[6];
    const float* ee_b2    = (const float*)d_in[7];
    const float* W1       = (const float*)d_in[8];
    const float* Ws       = (const float*)d_in[9];
    const float* att_src  = (const float*)d_in[10];
    const float* att_dst  = (const float*)d_in[11];
    const float* We       = (const float*)d_in[12];
    const float* att_e    = (const float*)d_in[13];
    const float* bias     = (const float*)d_in[14];
    const float* ln_g     = (const float*)d_in[15];
    const float* ln_b     = (const float*)d_in[16];
    const float* lin1_w   = (const float*)d_in[17];
    const float* lin1_b   = (const float*)d_in[18];
    const float* lin2_w   = (const float*)d_in[19];
    const float* lin2_b   = (const float*)d_in[20];
    float* out = (float*)d_out;

    // ---- workspace carve-up (256B aligned) ----
    char* ws = (char*)d_ws;
    size_t off = 0;
    auto alloc = [&](size_t bytes) -> char* {
        char* p = ws + off;
        off += (bytes + 255) & ~(size_t)255;
        return p;
    };
    float* ew      = (float*)alloc((size_t)ET * 4);
    float* ew_sum  = (float*)alloc(4);
    float* ce      = (float*)alloc(12 * 4);
    unsigned short* hbuf = (unsigned short*)alloc((size_t)NN * 256 * 2);
    float* asrc    = (float*)alloc((size_t)NN * 4 * 4);
    float* adst    = (float*)alloc((size_t)NN * 4 * 4);
    float* xi      = (float*)alloc((size_t)NN * 64 * 4);
    int*   deg     = (int*)alloc((size_t)NN * 4);       // reused as fill
    int*   row_ptr = (int*)alloc((size_t)(NN + 1) * 4);
    int*   csr_src = (int*)alloc((size_t)ET * 4);
    int*   csr_dst = (int*)alloc((size_t)ET * 4);
    float* csr_ew  = (float*)alloc((size_t)ET * 4);
    float4* alpha  = (float4*)alloc((size_t)ET * 16);
    (void)ws_size; (void)n_in; (void)in_sizes; (void)out_size;

    const int* ei_src = ei;
    const int* ei_dst = ei + NE;

    // 1. edge encoder
    hipMemsetAsync(ew_sum, 0, 4, stream);
    edge_mlp_kernel<<<(NE + 255) / 256, 256, 0, stream>>>(ea, ee_w1, ee_b1, ee_w2, ee_b2, ew, ew_sum);
    prep_kernel<<<(NN + 255) / 256, 256, 0, stream>>>(We, att_e, ew_sum, ew, ce);

    // 2. CSR by dst
    hipMemsetAsync(deg, 0, (size_t)NN * 4, stream);
    hist_kernel<<<(ET + 255) / 256, 256, 0, stream>>>(ei_dst, deg);
    scan_kernel<<<1, 1024, 0, stream>>>(deg, row_ptr);
    hipMemsetAsync(deg, 0, (size_t)NN * 4, stream);
    scatter_kernel<<<(ET + 255) / 256, 256, 0, stream>>>(ei_src, ei_dst, row_ptr, ew, deg,
                                                         csr_src, csr_dst, csr_ew);

    // 3. three GAT layers
    const int ntBlocks = (NN + 7) / 8;
    const int agBlocks = (NN + 3) / 4;
    const int aeBlocks = (ET + 255) / 256;
    // layer 0
    node_transform<16><<<ntBlocks, 256, 0, stream>>>(x, W1, att_src + 0 * 256, att_dst + 0 * 256,
                                                     hbuf, asrc, adst);
    alpha_kernel<<<aeBlocks, 256, 0, stream>>>(asrc, adst, csr_src, csr_dst, csr_ew, ce + 0 * 4, alpha);
    gat_aggregate<<<agBlocks, 256, 0, stream>>>(hbuf, (const float*)alpha, bias + 0 * 64,
                                                csr_src, row_ptr, xi, 0);
    // layers 1..2 (residual)
    for (int l = 0; l < 2; ++l) {
        node_transform<64><<<ntBlocks, 256, 0, stream>>>(xi, Ws + (size_t)l * 64 * 256,
                                                         att_src + (l + 1) * 256,
                                                         att_dst + (l + 1) * 256,
                                                         hbuf, asrc, adst);
        alpha_kernel<<<aeBlocks, 256, 0, stream>>>(asrc, adst, csr_src, csr_dst, csr_ew,
                                                   ce + (l + 1) * 4, alpha);
        gat_aggregate<<<agBlocks, 256, 0, stream>>>(hbuf, (const float*)alpha, bias + (l + 1) * 64,
                                                    csr_src, row_ptr, xi, 1);
    }

    // 4. readout
    readout_kernel<<<NB, 64, 0, stream>>>(xi, batch, ln_g, ln_b, lin1_w, lin1_b, lin2_w, lin2_b, out);
}

// Round 3
// 642.221 us; speedup vs baseline: 1.6555x; 1.1459x over previous
//
#include <hip/hip_runtime.h>
#include <cstddef>
#include <cstdint>

constexpr int NN = 50000;          // nodes
constexpr int NE = 800000;         // edges (no self loops)
constexpr int ET = NE + NN;        // edges + self loops
constexpr int NB = 50;             // graphs
constexpr int SCAN_B = 1024;
constexpr int NBLK = (NN + SCAN_B - 1) / SCAN_B;   // 49

__device__ __forceinline__ float eluf(float x) { return x > 0.f ? x : expm1f(x); }

// round-to-nearest-even fp32 -> bf16 (as ushort)
__device__ __forceinline__ unsigned short f2bf(float f) {
    unsigned int u = __float_as_uint(f);
    unsigned int r = (u + 0x7fffu + ((u >> 16) & 1u)) >> 16;
    return (unsigned short)r;
}

// ---------------- kernel: edge encoder MLP + sum(ew) ----------------
__global__ void edge_mlp_kernel(const float* __restrict__ ea,
                                const float* __restrict__ w1, const float* __restrict__ b1,
                                const float* __restrict__ w2, const float* __restrict__ b2,
                                float* __restrict__ ew, float* __restrict__ ew_sum) {
    __shared__ float sw1[320];
    __shared__ float sb1[64];
    __shared__ float sw2[64];
    int t = threadIdx.x;
    for (int i = t; i < 320; i += 256) sw1[i] = w1[i];
    if (t < 64) { sb1[t] = b1[t]; sw2[t] = w2[t]; }
    __syncthreads();
    int e = blockIdx.x * 256 + t;
    float val = 0.f;
    if (e < NE) {
        float a0 = ea[e*5+0], a1 = ea[e*5+1], a2 = ea[e*5+2], a3 = ea[e*5+3], a4 = ea[e*5+4];
        float acc = b2[0];
        #pragma unroll 8
        for (int j = 0; j < 64; ++j) {
            float hj = sb1[j] + a0*sw1[j] + a1*sw1[64+j] + a2*sw1[128+j] + a3*sw1[192+j] + a4*sw1[256+j];
            acc += fmaxf(hj, 0.f) * sw2[j];
        }
        val = 1.f / (1.f + expf(-acc));
        ew[e] = val;
    }
    __shared__ float red[256];
    red[t] = val;
    __syncthreads();
    for (int off = 128; off > 0; off >>= 1) {
        if (t < off) red[t] += red[t + off];
        __syncthreads();
    }
    if (t == 0) atomicAdd(ew_sum, red[0]);
}

// ---------------- kernel: fill self-loop ew with mean; compute ce[l][h] ----------------
__global__ void prep_kernel(const float* __restrict__ We, const float* __restrict__ att_e,
                            const float* __restrict__ ew_sum, float* __restrict__ ew,
                            float* __restrict__ ce) {
    int i = blockIdx.x * 256 + threadIdx.x;
    float mean = ew_sum[0] * (1.f / (float)NE);
    if (i < NN) ew[NE + i] = mean;
    if (i < 12) {
        int l = i >> 2, h = i & 3;
        float s = 0.f;
        for (int c = 0; c < 64; ++c)
            s += We[l*256 + h*64 + c] * att_e[l*256 + h*64 + c];
        ce[i] = s;
    }
}

// ---------------- CSR build ----------------
__global__ void hist_kernel(const int* __restrict__ ei_dst, int* __restrict__ deg) {
    int e = blockIdx.x * 256 + threadIdx.x;
    if (e >= ET) return;
    int d = (e < NE) ? ei_dst[e] : (e - NE);
    atomicAdd(&deg[d], 1);
}

// multi-block scan, phase A: per-block local inclusive scan + block sum
__global__ void scan_blocks(const int* __restrict__ deg, int* __restrict__ row_ptr,
                            int* __restrict__ bsum) {
    __shared__ int sdata[SCAN_B];
    int t = threadIdx.x;
    int i = blockIdx.x * SCAN_B + t;
    int v = (i < NN) ? deg[i] : 0;
    sdata[t] = v;
    __syncthreads();
    for (int off = 1; off < SCAN_B; off <<= 1) {
        int tv = (t >= off) ? sdata[t - off] : 0;
        __syncthreads();
        sdata[t] += tv;
        __syncthreads();
    }
    if (i < NN) row_ptr[i + 1] = sdata[t];
    if (t == SCAN_B - 1) bsum[blockIdx.x] = sdata[t];
}

// phase B: one wave exclusive-scans the block sums
__global__ void scan_bsum(const int* __restrict__ bsum, int* __restrict__ boff,
                          int* __restrict__ row_ptr) {
    int t = threadIdx.x;   // 64
    int v = (t < NBLK) ? bsum[t] : 0;
    int inc = v;
    #pragma unroll
    for (int off = 1; off < 64; off <<= 1) {
        int n = __shfl_up(inc, off);
        if (t >= off) inc += n;
    }
    boff[t] = inc - v;
    if (t == 0) row_ptr[0] = 0;
}

// phase C: add block offsets
__global__ void scan_add(const int* __restrict__ boff, int* __restrict__ row_ptr) {
    int i = blockIdx.x * 256 + threadIdx.x;
    if (i < NN) row_ptr[i + 1] += boff[i >> 10];
}

// write per-slot src / dst / ew so later kernels have no indirection
__global__ void scatter_kernel(const int* __restrict__ ei_src, const int* __restrict__ ei_dst,
                               const int* __restrict__ row_ptr, const float* __restrict__ ew,
                               int* __restrict__ fill, int* __restrict__ csr_src,
                               int* __restrict__ csr_dst, float* __restrict__ csr_ew) {
    int e = blockIdx.x * 256 + threadIdx.x;
    if (e >= ET) return;
    int d = (e < NE) ? ei_dst[e] : (e - NE);
    int s = (e < NE) ? ei_src[e] : (e - NE);
    int pos = atomicAdd(&fill[d], 1);
    int slot = row_ptr[d] + pos;
    csr_src[slot] = s;
    csr_dst[slot] = d;
    csr_ew[slot] = ew[e];
}

// ---------------- kernel: h = xin @ W (bf16 store), fused alpha_src/alpha_dst ----------------
template <int FIN>
__global__ void node_transform(const float* __restrict__ xin, const float* __restrict__ W,
                               const float* __restrict__ a_s, const float* __restrict__ a_d,
                               unsigned short* __restrict__ hb, float* __restrict__ asrc,
                               float* __restrict__ adst) {
    const int t = threadIdx.x;
    const int n0 = blockIdx.x * 8;
    __shared__ float xr[8 * FIN];
    for (int i = t; i < 8 * FIN; i += 256) {
        int node = n0 + i / FIN;
        xr[i] = (node < NN) ? xin[(size_t)node * FIN + (i % FIN)] : 0.f;
    }
    __syncthreads();
    float acc[8];
    #pragma unroll
    for (int i = 0; i < 8; ++i) acc[i] = 0.f;
    for (int k = 0; k < FIN; ++k) {
        float wv = W[k * 256 + t];
        #pragma unroll
        for (int i = 0; i < 8; ++i) acc[i] += xr[i * FIN + k] * wv;
    }
    float as_t = a_s[t], ad_t = a_d[t];
    int lane = t & 63, head = t >> 6;
    for (int i = 0; i < 8; ++i) {
        int node = n0 + i;
        if (node >= NN) break;
        hb[(size_t)node * 256 + t] = f2bf(acc[i]);
        float vs = acc[i] * as_t, vd = acc[i] * ad_t;
        #pragma unroll
        for (int mask = 1; mask <= 32; mask <<= 1) {
            vs += __shfl_xor(vs, mask);
            vd += __shfl_xor(vd, mask);
        }
        if (lane == 0) {
            asrc[node * 4 + head] = vs;
            adst[node * 4 + head] = vd;
        }
    }
}

// ---------------- kernel: per-slot p = exp(leaky_relu(alpha)), edge-parallel ----------------
// Safe without max-subtraction: |alpha| is O(1) (sums of 0.1-scale dot products),
// far from fp32 exp overflow (88); a = p/sum(p) is scale-invariant.
__global__ void p_kernel(const float* __restrict__ asrc, const float* __restrict__ adst,
                         const int* __restrict__ csr_src, const int* __restrict__ csr_dst,
                         const float* __restrict__ csr_ew, const float* __restrict__ ce_l,
                         float4* __restrict__ pbuf) {
    int ei = blockIdx.x * 256 + threadIdx.x;
    if (ei >= ET) return;
    int s = csr_src[ei];
    int d = csr_dst[ei];
    float w = csr_ew[ei];
    const float4 as4 = *(const float4*)(asrc + s * 4);
    const float4 ad4 = *(const float4*)(adst + d * 4);
    float4 o;
    float v;
    v = as4.x + ad4.x + w * ce_l[0]; o.x = expf(v > 0.f ? v : 0.2f * v);
    v = as4.y + ad4.y + w * ce_l[1]; o.y = expf(v > 0.f ? v : 0.2f * v);
    v = as4.z + ad4.z + w * ce_l[2]; o.z = expf(v > 0.f ? v : 0.2f * v);
    v = as4.w + ad4.w + w * ce_l[3]; o.w = expf(v > 0.f ? v : 0.2f * v);
    pbuf[ei] = o;
}

// ---------------- kernel: per-dst-node aggregation (single pass) ----------------
// One wave (64 lanes) per destination node. 4 waves / 256-thread block.
__global__ void gat_aggregate(const unsigned short* __restrict__ hb,
                              const float* __restrict__ pf,
                              const float* __restrict__ bias_l,
                              const int* __restrict__ csr_src, const int* __restrict__ row_ptr,
                              float* __restrict__ xi, int residual) {
    int widx = (blockIdx.x * 256 + threadIdx.x) >> 6;   // node
    if (widx >= NN) return;
    int lane = threadIdx.x & 63;
    int start = row_ptr[widx], end = row_ptr[widx + 1];
    int head2 = lane >> 4;

    float psum = 0.f;
    float ax = 0.f, ay = 0.f, az = 0.f, aw = 0.f;
    int ei = start;
    for (; ei + 1 < end; ei += 2) {
        int s0 = csr_src[ei];
        int s1 = csr_src[ei + 1];
        float p0 = pf[ei * 4 + head2];
        float p1 = pf[(ei + 1) * 4 + head2];
        const uint2 q0 = *(const uint2*)(hb + (size_t)s0 * 256 + lane * 4);
        const uint2 q1 = *(const uint2*)(hb + (size_t)s1 * 256 + lane * 4);
        psum += p0 + p1;
        ax += p0 * __uint_as_float(q0.x << 16) + p1 * __uint_as_float(q1.x << 16);
        ay += p0 * __uint_as_float(q0.x & 0xffff0000u) + p1 * __uint_as_float(q1.x & 0xffff0000u);
        az += p0 * __uint_as_float(q0.y << 16) + p1 * __uint_as_float(q1.y << 16);
        aw += p0 * __uint_as_float(q0.y & 0xffff0000u) + p1 * __uint_as_float(q1.y & 0xffff0000u);
    }
    if (ei < end) {
        int s0 = csr_src[ei];
        float p0 = pf[ei * 4 + head2];
        const uint2 q0 = *(const uint2*)(hb + (size_t)s0 * 256 + lane * 4);
        psum += p0;
        ax += p0 * __uint_as_float(q0.x << 16);
        ay += p0 * __uint_as_float(q0.x & 0xffff0000u);
        az += p0 * __uint_as_float(q0.y << 16);
        aw += p0 * __uint_as_float(q0.y & 0xffff0000u);
    }
    float inv = 1.f / (psum + 1e-16f);
    ax *= inv; ay *= inv; az *= inv; aw *= inv;

    // ---- head mean: lanes {c,c+16,c+32,c+48} hold the 4 heads of channel group c ----
    #pragma unroll
    for (int mask = 16; mask <= 32; mask <<= 1) {
        ax += __shfl_xor(ax, mask);
        ay += __shfl_xor(ay, mask);
        az += __shfl_xor(az, mask);
        aw += __shfl_xor(aw, mask);
    }
    if (lane < 16) {
        int c0 = lane * 4;
        float4 v;
        v.x = 0.25f * ax + bias_l[c0 + 0];
        v.y = 0.25f * ay + bias_l[c0 + 1];
        v.z = 0.25f * az + bias_l[c0 + 2];
        v.w = 0.25f * aw + bias_l[c0 + 3];
        float* xo = xi + (size_t)widx * 64 + c0;
        if (residual) {
            const float4 p = *(const float4*)xo;
            v.x += p.x; v.y += p.y; v.z += p.z; v.w += p.w;
        }
        v.x = eluf(v.x); v.y = eluf(v.y); v.z = eluf(v.z); v.w = eluf(v.w);
        *(float4*)xo = v;
    }
}

// ---------------- kernel: LN + 2-layer MLP on the 50 target nodes ----------------
__global__ void readout_kernel(const float* __restrict__ xi, const int* __restrict__ batch,
                               const float* __restrict__ ln_g, const float* __restrict__ ln_b,
                               const float* __restrict__ l1w, const float* __restrict__ l1b,
                               const float* __restrict__ l2w, const float* __restrict__ l2b,
                               float* __restrict__ out) {
    int b = blockIdx.x;
    int t = threadIdx.x;   // 64 threads, one wave
    __shared__ int tg_s;
    if (t == 0) {
        int lo = 0, hi = NN;
        while (lo < hi) {
            int mid = (lo + hi) >> 1;
            if (batch[mid] < b) lo = mid + 1; else hi = mid;
        }
        tg_s = lo;
    }
    __syncthreads();
    int tg = tg_s;
    float x = xi[(size_t)tg * 64 + t];
    float s = x;
    #pragma unroll
    for (int mask = 1; mask <= 32; mask <<= 1) s += __shfl_xor(s, mask);
    float mu = s * (1.f / 64.f);
    float d = x - mu;
    float v = d * d;
    #pragma unroll
    for (int mask = 1; mask <= 32; mask <<= 1) v += __shfl_xor(v, mask);
    float var = v * (1.f / 64.f);
    float xn = d * rsqrtf(var + 1e-5f) * ln_g[t] + ln_b[t];
    __shared__ float sx[64];
    sx[t] = xn;
    __syncthreads();
    float acc = l1b[t];
    for (int k = 0; k < 64; ++k) acc += sx[k] * l1w[k * 64 + t];
    acc = eluf(acc);
    __shared__ float st[64];
    st[t] = acc;
    __syncthreads();
    if (t < 3) {
        float o = l2b[t];
        for (int k = 0; k < 64; ++k) o += st[k] * l2w[k * 3 + t];
        out[b * 3 + t] = o;
    }
}

extern "C" void kernel_launch(void* const* d_in, const int* in_sizes, int n_in,
                              void* d_out, int out_size, void* d_ws, size_t ws_size,
                              hipStream_t stream) {
    const float* x        = (const float*)d_in[0];
    const int*   ei       = (const int*)d_in[1];
    const float* ea       = (const float*)d_in[2];
    const int*   batch    = (const int*)d_in[3];
    const float* ee_w1    = (const float*)d_in[4];
    const float* ee_b1    = (const float*)d_in[5];
    const float* ee_w2    = (const float*)d_in[6];
    const float* ee_b2    = (const float*)d_in[7];
    const float* W1       = (const float*)d_in[8];
    const float* Ws       = (const float*)d_in[9];
    const float* att_src  = (const float*)d_in[10];
    const float* att_dst  = (const float*)d_in[11];
    const float* We       = (const float*)d_in[12];
    const float* att_e    = (const float*)d_in[13];
    const float* bias     = (const float*)d_in[14];
    const float* ln_g     = (const float*)d_in[15];
    const float* ln_b     = (const float*)d_in[16];
    const float* lin1_w   = (const float*)d_in[17];
    const float* lin1_b   = (const float*)d_in[18];
    const float* lin2_w   = (const float*)d_in[19];
    const float* lin2_b   = (const float*)d_in[20];
    float* out = (float*)d_out;

    // ---- workspace carve-up (256B aligned) ----
    char* ws = (char*)d_ws;
    size_t off = 0;
    auto alloc = [&](size_t bytes) -> char* {
        char* p = ws + off;
        off += (bytes + 255) & ~(size_t)255;
        return p;
    };
    float* ew      = (float*)alloc((size_t)ET * 4);
    float* ew_sum  = (float*)alloc(4);
    float* ce      = (float*)alloc(12 * 4);
    unsigned short* hbuf = (unsigned short*)alloc((size_t)NN * 256 * 2);
    float* asrc    = (float*)alloc((size_t)NN * 4 * 4);
    float* adst    = (float*)alloc((size_t)NN * 4 * 4);
    float* xi      = (float*)alloc((size_t)NN * 64 * 4);
    int*   deg     = (int*)alloc((size_t)NN * 4);       // reused as fill
    int*   row_ptr = (int*)alloc((size_t)(NN + 1) * 4);
    int*   bsum    = (int*)alloc(64 * 4);
    int*   boff    = (int*)alloc(64 * 4);
    int*   csr_src = (int*)alloc((size_t)ET * 4);
    int*   csr_dst = (int*)alloc((size_t)ET * 4);
    float* csr_ew  = (float*)alloc((size_t)ET * 4);
    float4* pbuf   = (float4*)alloc((size_t)ET * 16);
    (void)ws_size; (void)n_in; (void)in_sizes; (void)out_size;

    const int* ei_src = ei;
    const int* ei_dst = ei + NE;

    // 1. edge encoder
    hipMemsetAsync(ew_sum, 0, 4, stream);
    edge_mlp_kernel<<<(NE + 255) / 256, 256, 0, stream>>>(ea, ee_w1, ee_b1, ee_w2, ee_b2, ew, ew_sum);
    prep_kernel<<<(NN + 255) / 256, 256, 0, stream>>>(We, att_e, ew_sum, ew, ce);

    // 2. CSR by dst (multi-block scan)
    hipMemsetAsync(deg, 0, (size_t)NN * 4, stream);
    hist_kernel<<<(ET + 255) / 256, 256, 0, stream>>>(ei_dst, deg);
    scan_blocks<<<NBLK, SCAN_B, 0, stream>>>(deg, row_ptr, bsum);
    scan_bsum<<<1, 64, 0, stream>>>(bsum, boff, row_ptr);
    scan_add<<<(NN + 255) / 256, 256, 0, stream>>>(boff, row_ptr);
    hipMemsetAsync(deg, 0, (size_t)NN * 4, stream);
    scatter_kernel<<<(ET + 255) / 256, 256, 0, stream>>>(ei_src, ei_dst, row_ptr, ew, deg,
                                                         csr_src, csr_dst, csr_ew);

    // 3. three GAT layers
    const int ntBlocks = (NN + 7) / 8;
    const int agBlocks = (NN + 3) / 4;
    const int aeBlocks = (ET + 255) / 256;
    // layer 0
    node_transform<16><<<ntBlocks, 256, 0, stream>>>(x, W1, att_src + 0 * 256, att_dst + 0 * 256,
                                                     hbuf, asrc, adst);
    p_kernel<<<aeBlocks, 256, 0, stream>>>(asrc, adst, csr_src, csr_dst, csr_ew, ce + 0 * 4, pbuf);
    gat_aggregate<<<agBlocks, 256, 0, stream>>>(hbuf, (const float*)pbuf, bias + 0 * 64,
                                                csr_src, row_ptr, xi, 0);
    // layers 1..2 (residual)
    for (int l = 0; l < 2; ++l) {
        node_transform<64><<<ntBlocks, 256, 0, stream>>>(xi, Ws + (size_t)l * 64 * 256,
                                                         att_src + (l + 1) * 256,
                                                         att_dst + (l + 1) * 256,
                                                         hbuf, asrc, adst);
        p_kernel<<<aeBlocks, 256, 0, stream>>>(asrc, adst, csr_src, csr_dst, csr_ew,
                                               ce + (l + 1) * 4, pbuf);
        gat_aggregate<<<agBlocks, 256, 0, stream>>>(hbuf, (const float*)pbuf, bias + (l + 1) * 64,
                                                    csr_src, row_ptr, xi, 1);
    }

    // 4. readout
    readout_kernel<<<NB, 64, 0, stream>>>(xi, batch, ln_g, ln_b, lin1_w, lin1_b, lin2_w, lin2_b, out);
}

// Round 4
// 614.250 us; speedup vs baseline: 1.7309x; 1.0455x over previous
//
#include <hip/hip_runtime.h>
#include <cstddef>
#include <cstdint>

constexpr int NN = 50000;          // nodes
constexpr int NE = 800000;         // edges (no self loops)
constexpr int ET = NE + NN;        // edges + self loops
constexpr int NB = 50;             // graphs
constexpr int SCAN_B = 1024;
constexpr int NBLK = (NN + SCAN_B - 1) / SCAN_B;   // 49

__device__ __forceinline__ float eluf(float x) { return x > 0.f ? x : expm1f(x); }

// round-to-nearest-even fp32 -> bf16 (as ushort)
__device__ __forceinline__ unsigned short f2bf(float f) {
    unsigned int u = __float_as_uint(f);
    unsigned int r = (u + 0x7fffu + ((u >> 16) & 1u)) >> 16;
    return (unsigned short)r;
}

// ---------------- kernel: edge encoder MLP + sum(ew) ----------------
__global__ void edge_mlp_kernel(const float* __restrict__ ea,
                                const float* __restrict__ w1, const float* __restrict__ b1,
                                const float* __restrict__ w2, const float* __restrict__ b2,
                                float* __restrict__ ew, float* __restrict__ ew_sum) {
    __shared__ float sw1[320];
    __shared__ float sb1[64];
    __shared__ float sw2[64];
    int t = threadIdx.x;
    for (int i = t; i < 320; i += 256) sw1[i] = w1[i];
    if (t < 64) { sb1[t] = b1[t]; sw2[t] = w2[t]; }
    __syncthreads();
    int e = blockIdx.x * 256 + t;
    float val = 0.f;
    if (e < NE) {
        float a0 = ea[e*5+0], a1 = ea[e*5+1], a2 = ea[e*5+2], a3 = ea[e*5+3], a4 = ea[e*5+4];
        float acc = b2[0];
        #pragma unroll 8
        for (int j = 0; j < 64; ++j) {
            float hj = sb1[j] + a0*sw1[j] + a1*sw1[64+j] + a2*sw1[128+j] + a3*sw1[192+j] + a4*sw1[256+j];
            acc += fmaxf(hj, 0.f) * sw2[j];
        }
        val = 1.f / (1.f + expf(-acc));
        ew[e] = val;
    }
    __shared__ float red[256];
    red[t] = val;
    __syncthreads();
    for (int off = 128; off > 0; off >>= 1) {
        if (t < off) red[t] += red[t + off];
        __syncthreads();
    }
    if (t == 0) atomicAdd(ew_sum, red[0]);
}

// ---------------- kernel: fill self-loop ew with mean; compute ce[l][h] ----------------
__global__ void prep_kernel(const float* __restrict__ We, const float* __restrict__ att_e,
                            const float* __restrict__ ew_sum, float* __restrict__ ew,
                            float* __restrict__ ce) {
    int i = blockIdx.x * 256 + threadIdx.x;
    float mean = ew_sum[0] * (1.f / (float)NE);
    if (i < NN) ew[NE + i] = mean;
    if (i < 12) {
        int l = i >> 2, h = i & 3;
        float s = 0.f;
        for (int c = 0; c < 64; ++c)
            s += We[l*256 + h*64 + c] * att_e[l*256 + h*64 + c];
        ce[i] = s;
    }
}

// ---------------- CSR build ----------------
__global__ void hist_kernel(const int* __restrict__ ei_dst, int* __restrict__ deg) {
    int e = blockIdx.x * 256 + threadIdx.x;
    if (e >= ET) return;
    int d = (e < NE) ? ei_dst[e] : (e - NE);
    atomicAdd(&deg[d], 1);
}

// multi-block scan, phase A: per-block local inclusive scan + block sum
__global__ void scan_blocks(const int* __restrict__ deg, int* __restrict__ row_ptr,
                            int* __restrict__ bsum) {
    __shared__ int sdata[SCAN_B];
    int t = threadIdx.x;
    int i = blockIdx.x * SCAN_B + t;
    int v = (i < NN) ? deg[i] : 0;
    sdata[t] = v;
    __syncthreads();
    for (int off = 1; off < SCAN_B; off <<= 1) {
        int tv = (t >= off) ? sdata[t - off] : 0;
        __syncthreads();
        sdata[t] += tv;
        __syncthreads();
    }
    if (i < NN) row_ptr[i + 1] = sdata[t];
    if (t == SCAN_B - 1) bsum[blockIdx.x] = sdata[t];
}

// phase B: one wave exclusive-scans the block sums
__global__ void scan_bsum(const int* __restrict__ bsum, int* __restrict__ boff,
                          int* __restrict__ row_ptr) {
    int t = threadIdx.x;   // 64
    int v = (t < NBLK) ? bsum[t] : 0;
    int inc = v;
    #pragma unroll
    for (int off = 1; off < 64; off <<= 1) {
        int n = __shfl_up(inc, off);
        if (t >= off) inc += n;
    }
    boff[t] = inc - v;
    if (t == 0) row_ptr[0] = 0;
}

// phase C: add block offsets
__global__ void scan_add(const int* __restrict__ boff, int* __restrict__ row_ptr) {
    int i = blockIdx.x * 256 + threadIdx.x;
    if (i < NN) row_ptr[i + 1] += boff[i >> 10];
}

// write per-slot src / ew so later kernels have no indirection
__global__ void scatter_kernel(const int* __restrict__ ei_src, const int* __restrict__ ei_dst,
                               const int* __restrict__ row_ptr, const float* __restrict__ ew,
                               int* __restrict__ fill, int* __restrict__ csr_src,
                               float* __restrict__ csr_ew) {
    int e = blockIdx.x * 256 + threadIdx.x;
    if (e >= ET) return;
    int d = (e < NE) ? ei_dst[e] : (e - NE);
    int s = (e < NE) ? ei_src[e] : (e - NE);
    int pos = atomicAdd(&fill[d], 1);
    int slot = row_ptr[d] + pos;
    csr_src[slot] = s;
    csr_ew[slot] = ew[e];
}

// ---------------- kernel: h = xin @ W (bf16 store), fused alpha_src/alpha_dst ----------------
template <int FIN>
__global__ void node_transform(const float* __restrict__ xin, const float* __restrict__ W,
                               const float* __restrict__ a_s, const float* __restrict__ a_d,
                               unsigned short* __restrict__ hb, float* __restrict__ asrc,
                               float* __restrict__ adst) {
    const int t = threadIdx.x;
    const int n0 = blockIdx.x * 8;
    __shared__ float xr[8 * FIN];
    for (int i = t; i < 8 * FIN; i += 256) {
        int node = n0 + i / FIN;
        xr[i] = (node < NN) ? xin[(size_t)node * FIN + (i % FIN)] : 0.f;
    }
    __syncthreads();
    float acc[8];
    #pragma unroll
    for (int i = 0; i < 8; ++i) acc[i] = 0.f;
    for (int k = 0; k < FIN; ++k) {
        float wv = W[k * 256 + t];
        #pragma unroll
        for (int i = 0; i < 8; ++i) acc[i] += xr[i * FIN + k] * wv;
    }
    float as_t = a_s[t], ad_t = a_d[t];
    int lane = t & 63, head = t >> 6;
    for (int i = 0; i < 8; ++i) {
        int node = n0 + i;
        if (node >= NN) break;
        hb[(size_t)node * 256 + t] = f2bf(acc[i]);
        float vs = acc[i] * as_t, vd = acc[i] * ad_t;
        #pragma unroll
        for (int mask = 1; mask <= 32; mask <<= 1) {
            vs += __shfl_xor(vs, mask);
            vd += __shfl_xor(vd, mask);
        }
        if (lane == 0) {
            asrc[node * 4 + head] = vs;
            adst[node * 4 + head] = vd;
        }
    }
}

// ---------------- kernel: per-dst-node softmax-free aggregation ----------------
// One wave per destination node; lane half h processes edges start+h, start+h+2,...
// Each of 32 lanes in a half loads uint4 = 8 bf16 channels (16 B) of h[src].
// p = exp(leaky_relu(alpha)) computed in-loop (no max-subtraction: |alpha| = O(1)).
__global__ void gat_aggregate(const unsigned short* __restrict__ hb,
                              const float* __restrict__ asrc, const float* __restrict__ adst,
                              const float* __restrict__ csr_ew, const float* __restrict__ ce_l,
                              const float* __restrict__ bias_l,
                              const int* __restrict__ csr_src, const int* __restrict__ row_ptr,
                              float* __restrict__ xi, int residual) {
    int widx = (blockIdx.x * 256 + threadIdx.x) >> 6;   // node
    if (widx >= NN) return;
    int lane = threadIdx.x & 63;
    int half = lane >> 5;
    int li = lane & 31;        // lane within half; channels li*8 .. li*8+7
    int head = li >> 3;        // 4 heads x 8 lanes
    int start = row_ptr[widx], end = row_ptr[widx + 1];
    float adw = adst[widx * 4 + head];
    float ceh = ce_l[head];

    float acc[8];
    #pragma unroll
    for (int r = 0; r < 8; ++r) acc[r] = 0.f;
    float psum = 0.f;

    #define PROC(EI)                                                                  \
        {                                                                             \
            int s = csr_src[EI];                                                      \
            float w = csr_ew[EI];                                                     \
            const uint4 q = *(const uint4*)(hb + (size_t)s * 256 + li * 8);           \
            float v = asrc[s * 4 + head] + adw + w * ceh;                             \
            v = v > 0.f ? v : 0.2f * v;                                               \
            float p = expf(v);                                                        \
            psum += p;                                                                \
            acc[0] += p * __uint_as_float(q.x << 16);                                 \
            acc[1] += p * __uint_as_float(q.x & 0xffff0000u);                         \
            acc[2] += p * __uint_as_float(q.y << 16);                                 \
            acc[3] += p * __uint_as_float(q.y & 0xffff0000u);                         \
            acc[4] += p * __uint_as_float(q.z << 16);                                 \
            acc[5] += p * __uint_as_float(q.z & 0xffff0000u);                         \
            acc[6] += p * __uint_as_float(q.w << 16);                                 \
            acc[7] += p * __uint_as_float(q.w & 0xffff0000u);                         \
        }

    int ei = start + half;
    for (; ei + 2 < end; ei += 4) {   // 2 edges per half per iter -> 2 gathers in flight
        PROC(ei);
        PROC(ei + 2);
    }
    if (ei < end) PROC(ei);
    #undef PROC

    // combine the two halves (same channels, disjoint edge sets)
    psum += __shfl_xor(psum, 32);
    #pragma unroll
    for (int r = 0; r < 8; ++r) acc[r] += __shfl_xor(acc[r], 32);

    float inv = 1.f / (psum + 1e-16f);
    #pragma unroll
    for (int r = 0; r < 8; ++r) acc[r] *= inv;

    // head mean: lanes li, li^8, li^16, li^24 hold same local channel, different heads
    #pragma unroll
    for (int r = 0; r < 8; ++r) {
        acc[r] += __shfl_xor(acc[r], 8);
        acc[r] += __shfl_xor(acc[r], 16);
        acc[r] *= 0.25f;
    }

    if (lane < 8) {
        int c0 = lane * 8;
        const float4 b0 = *(const float4*)(bias_l + c0);
        const float4 b1 = *(const float4*)(bias_l + c0 + 4);
        float4 v0, v1;
        v0.x = acc[0] + b0.x; v0.y = acc[1] + b0.y; v0.z = acc[2] + b0.z; v0.w = acc[3] + b0.w;
        v1.x = acc[4] + b1.x; v1.y = acc[5] + b1.y; v1.z = acc[6] + b1.z; v1.w = acc[7] + b1.w;
        float* xo = xi + (size_t)widx * 64 + c0;
        if (residual) {
            const float4 p0 = *(const float4*)xo;
            const float4 p1 = *(const float4*)(xo + 4);
            v0.x += p0.x; v0.y += p0.y; v0.z += p0.z; v0.w += p0.w;
            v1.x += p1.x; v1.y += p1.y; v1.z += p1.z; v1.w += p1.w;
        }
        v0.x = eluf(v0.x); v0.y = eluf(v0.y); v0.z = eluf(v0.z); v0.w = eluf(v0.w);
        v1.x = eluf(v1.x); v1.y = eluf(v1.y); v1.z = eluf(v1.z); v1.w = eluf(v1.w);
        *(float4*)xo = v0;
        *(float4*)(xo + 4) = v1;
    }
}

// ---------------- kernel: LN + 2-layer MLP on the 50 target nodes ----------------
__global__ void readout_kernel(const float* __restrict__ xi, const int* __restrict__ batch,
                               const float* __restrict__ ln_g, const float* __restrict__ ln_b,
                               const float* __restrict__ l1w, const float* __restrict__ l1b,
                               const float* __restrict__ l2w, const float* __restrict__ l2b,
                               float* __restrict__ out) {
    int b = blockIdx.x;
    int t = threadIdx.x;   // 64 threads, one wave
    __shared__ int tg_s;
    if (t == 0) {
        int lo = 0, hi = NN;
        while (lo < hi) {
            int mid = (lo + hi) >> 1;
            if (batch[mid] < b) lo = mid + 1; else hi = mid;
        }
        tg_s = lo;
    }
    __syncthreads();
    int tg = tg_s;
    float x = xi[(size_t)tg * 64 + t];
    float s = x;
    #pragma unroll
    for (int mask = 1; mask <= 32; mask <<= 1) s += __shfl_xor(s, mask);
    float mu = s * (1.f / 64.f);
    float d = x - mu;
    float v = d * d;
    #pragma unroll
    for (int mask = 1; mask <= 32; mask <<= 1) v += __shfl_xor(v, mask);
    float var = v * (1.f / 64.f);
    float xn = d * rsqrtf(var + 1e-5f) * ln_g[t] + ln_b[t];
    __shared__ float sx[64];
    sx[t] = xn;
    __syncthreads();
    float acc = l1b[t];
    for (int k = 0; k < 64; ++k) acc += sx[k] * l1w[k * 64 + t];
    acc = eluf(acc);
    __shared__ float st[64];
    st[t] = acc;
    __syncthreads();
    if (t < 3) {
        float o = l2b[t];
        for (int k = 0; k < 64; ++k) o += st[k] * l2w[k * 3 + t];
        out[b * 3 + t] = o;
    }
}

extern "C" void kernel_launch(void* const* d_in, const int* in_sizes, int n_in,
                              void* d_out, int out_size, void* d_ws, size_t ws_size,
                              hipStream_t stream) {
    const float* x        = (const float*)d_in[0];
    const int*   ei       = (const int*)d_in[1];
    const float* ea       = (const float*)d_in[2];
    const int*   batch    = (const int*)d_in[3];
    const float* ee_w1    = (const float*)d_in[4];
    const float* ee_b1    = (const float*)d_in[5];
    const float* ee_w2    = (const float*)d_in[6];
    const float* ee_b2    = (const float*)d_in[7];
    const float* W1       = (const float*)d_in[8];
    const float* Ws       = (const float*)d_in[9];
    const float* att_src  = (const float*)d_in[10];
    const float* att_dst  = (const float*)d_in[11];
    const float* We       = (const float*)d_in[12];
    const float* att_e    = (const float*)d_in[13];
    const float* bias     = (const float*)d_in[14];
    const float* ln_g     = (const float*)d_in[15];
    const float* ln_b     = (const float*)d_in[16];
    const float* lin1_w   = (const float*)d_in[17];
    const float* lin1_b   = (const float*)d_in[18];
    const float* lin2_w   = (const float*)d_in[19];
    const float* lin2_b   = (const float*)d_in[20];
    float* out = (float*)d_out;

    // ---- workspace carve-up (256B aligned) ----
    char* ws = (char*)d_ws;
    size_t off = 0;
    auto alloc = [&](size_t bytes) -> char* {
        char* p = ws + off;
        off += (bytes + 255) & ~(size_t)255;
        return p;
    };
    float* ew      = (float*)alloc((size_t)ET * 4);
    float* ew_sum  = (float*)alloc(4);
    float* ce      = (float*)alloc(12 * 4);
    unsigned short* hbuf = (unsigned short*)alloc((size_t)NN * 256 * 2);
    float* asrc    = (float*)alloc((size_t)NN * 4 * 4);
    float* adst    = (float*)alloc((size_t)NN * 4 * 4);
    float* xi      = (float*)alloc((size_t)NN * 64 * 4);
    int*   deg     = (int*)alloc((size_t)NN * 2 * 4);   // [0..NN) = deg, [NN..2NN) = fill
    int*   fill    = deg + NN;
    int*   row_ptr = (int*)alloc((size_t)(NN + 1) * 4);
    int*   bsum    = (int*)alloc(64 * 4);
    int*   boff    = (int*)alloc(64 * 4);
    int*   csr_src = (int*)alloc((size_t)ET * 4);
    float* csr_ew  = (float*)alloc((size_t)ET * 4);
    (void)ws_size; (void)n_in; (void)in_sizes; (void)out_size;

    const int* ei_src = ei;
    const int* ei_dst = ei + NE;

    // 1. edge encoder
    hipMemsetAsync(ew_sum, 0, 4, stream);
    edge_mlp_kernel<<<(NE + 255) / 256, 256, 0, stream>>>(ea, ee_w1, ee_b1, ee_w2, ee_b2, ew, ew_sum);
    prep_kernel<<<(NN + 255) / 256, 256, 0, stream>>>(We, att_e, ew_sum, ew, ce);

    // 2. CSR by dst (multi-block scan); one memset covers deg + fill
    hipMemsetAsync(deg, 0, (size_t)NN * 2 * 4, stream);
    hist_kernel<<<(ET + 255) / 256, 256, 0, stream>>>(ei_dst, deg);
    scan_blocks<<<NBLK, SCAN_B, 0, stream>>>(deg, row_ptr, bsum);
    scan_bsum<<<1, 64, 0, stream>>>(bsum, boff, row_ptr);
    scan_add<<<(NN + 255) / 256, 256, 0, stream>>>(boff, row_ptr);
    scatter_kernel<<<(ET + 255) / 256, 256, 0, stream>>>(ei_src, ei_dst, row_ptr, ew, fill,
                                                         csr_src, csr_ew);

    // 3. three GAT layers
    const int ntBlocks = (NN + 7) / 8;
    const int agBlocks = (NN + 3) / 4;
    // layer 0
    node_transform<16><<<ntBlocks, 256, 0, stream>>>(x, W1, att_src + 0 * 256, att_dst + 0 * 256,
                                                     hbuf, asrc, adst);
    gat_aggregate<<<agBlocks, 256, 0, stream>>>(hbuf, asrc, adst, csr_ew, ce + 0 * 4,
                                                bias + 0 * 64, csr_src, row_ptr, xi, 0);
    // layers 1..2 (residual)
    for (int l = 0; l < 2; ++l) {
        node_transform<64><<<ntBlocks, 256, 0, stream>>>(xi, Ws + (size_t)l * 64 * 256,
                                                         att_src + (l + 1) * 256,
                                                         att_dst + (l + 1) * 256,
                                                         hbuf, asrc, adst);
        gat_aggregate<<<agBlocks, 256, 0, stream>>>(hbuf, asrc, adst, csr_ew, ce + (l + 1) * 4,
                                                    bias + (l + 1) * 64, csr_src, row_ptr, xi, 1);
    }

    // 4. readout
    readout_kernel<<<NB, 64, 0, stream>>>(xi, batch, ln_g, ln_b, lin1_w, lin1_b, lin2_w, lin2_b, out);
}